// Round 3
// baseline (643.410 us; speedup 1.0000x reference)
//
#include <hip/hip_runtime.h>
#include <hip/hip_bf16.h>

#define T_DIM 7
#define H_DIM 96
#define W_DIM 96
#define HW    (H_DIM*W_DIM)          // 9216
#define L_DIM (T_DIM*HW)             // 64512
#define NTAPS 27

typedef __attribute__((ext_vector_type(8))) short bf16x8;
typedef __attribute__((ext_vector_type(4))) float f32x4;

// swizzle: rotate 16B slot within a 128B row by row&7 (conflict-floor for b128)
__device__ __forceinline__ int swz(int row, int colbyte) {
    return row * 128 + ((((colbyte >> 4) + row) & 7) << 4) + (colbyte & 15);
}

// ---------------------------------------------------------------------------
// prep_weights: [O][C][27] fp32 -> [27][O(64-pad)][C] bf16, 4 tensors.
// ---------------------------------------------------------------------------
__global__ void prep_weights(const float* __restrict__ woff0,
                             const float* __restrict__ w0,
                             const float* __restrict__ woff1,
                             const float* __restrict__ w1,
                             unsigned short* __restrict__ dst)
{
    int idx = blockIdx.x * 256 + threadIdx.x;
    const int per = NTAPS * 64 * 64;           // 110592
    if (idx >= 4 * per) return;
    int which = idx / per;
    int r     = idx % per;
    int tap   = r / 4096;
    int o     = (r >> 6) & 63;
    int c     = r & 63;
    const float* src = (which == 0) ? woff0 : (which == 1) ? w0
                     : (which == 2) ? woff1 : w1;
    int omax = (which == 0 || which == 2) ? 54 : 64;
    float v = 0.f;
    if (o < omax) v = src[(o * 64 + c) * NTAPS + tap];
    __hip_bfloat16 h = __float2bfloat16(v);
    dst[idx] = *reinterpret_cast<unsigned short*>(&h);
}

// ---------------------------------------------------------------------------
// transpose_x: x [C=64][L] fp32 -> xt [L][64] bf16 (stored as packed dwords)
// ---------------------------------------------------------------------------
__global__ void transpose_x(const float* __restrict__ x, unsigned* __restrict__ xt2)
{
    __shared__ float tile[64][65];
    const int tid = threadIdx.x;
    const int lb  = blockIdx.x * 64;
    const int ln  = tid & 63;
    const int q   = tid >> 6;    // 0..3
#pragma unroll
    for (int i = 0; i < 16; ++i) {
        int c = q + 4 * i;
        tile[ln][c] = x[(size_t)c * L_DIM + lb + ln];
    }
    __syncthreads();
    const int ln2 = tid & 31, q2 = tid >> 5;   // 0..7
#pragma unroll
    for (int i = 0; i < 8; ++i) {
        int ll = q2 + 8 * i;
        __hip_bfloat162 h2 = __float22bfloat162_rn(make_float2(tile[ll][2*ln2], tile[ll][2*ln2+1]));
        xt2[(size_t)(lb + ll) * 32 + ln2] = *reinterpret_cast<unsigned*>(&h2);
    }
}

// ---------------------------------------------------------------------------
// dcn_wave: barrier-free. Each wave owns 16 locations x 64 out channels.
//   DEFORM=false : integer-shift sampling (offset conv)
//   DEFORM=true  : 4-corner bilinear with per-(loc,tap) offsets
//   EPI: 0 = +bias -> f32 [loc][64]; 1 = +bias+leaky -> bf16 [loc][64];
//        2 = +bias+residual -> f32 NCDHW d_out
// ---------------------------------------------------------------------------
template<bool DEFORM, int EPI>
__global__ __launch_bounds__(256, 3)
void dcn_wave(const unsigned short* __restrict__ xin,   // bf16 [L][64]
              const float* __restrict__ off,            // f32 [L][64] (DEFORM)
              const unsigned short* __restrict__ Wt,    // bf16 [27][64][64] [tap][o][c]
              const float* __restrict__ bias, int nbias,
              const float* __restrict__ resid,          // f32 NCDHW (EPI==2)
              float* __restrict__ outf,
              unsigned short* __restrict__ outh)
{
    __shared__ __align__(16) unsigned char smem[16384];  // 4KB per wave
    const int tid  = threadIdx.x;
    const int wave = tid >> 6, lane = tid & 63;
    const int lr   = lane & 15, lk = lane >> 4;          // loc-in-wave / ch-group
    unsigned char* Sb = smem + wave * 4096;

    const int nt    = HW / 64;                 // 144
    const int tile  = blockIdx.x % nt;
    const int t     = blockIdx.x / nt;
    const int wloc0 = tile * 64 + wave * 16;
    const int lbase = t * HW + wloc0;

    const int mypos = wloc0 + lr;
    const int h = mypos / W_DIM;
    const int w = mypos - h * W_DIM;

    f32x4 acc[4];
#pragma unroll
    for (int n = 0; n < 4; ++n) acc[n] = (f32x4){0.f, 0.f, 0.f, 0.f};

    const unsigned char* xb = (const unsigned char*)xin;
    const float* offp = DEFORM ? (off + (size_t)(lbase + lr) * 64) : nullptr;

    int4  g[8];
    float cw[4];
    int   cb[4];
    float2 o2n = make_float2(0.f, 0.f);

    auto params = [&](int k, float2 o2) {
        int kt = k / 9; int r9 = k - kt * 9;
        int kh = r9 / 3; int kw = r9 - kh * 3;
        int tp = t + kt - 1;
        bool tv = (tp >= 0) && (tp < T_DIM);
        int tb = (tv ? tp : 0) * HW;
        if (DEFORM) {
            float ph = (float)(h + kh - 1) + o2.x;
            float pw = (float)(w + kw - 1) + o2.y;
            float h0f = floorf(ph), w0f = floorf(pw);
            float lh = ph - h0f, lw = pw - w0f;
            int h0 = (int)h0f, w0 = (int)w0f;
#pragma unroll
            for (int j = 0; j < 4; ++j) {
                int hj = h0 + (j >> 1), wj = w0 + (j & 1);
                bool v = tv && (hj >= 0) && (hj < H_DIM) && (wj >= 0) && (wj < W_DIM);
                float wh  = (j >> 1) ? lh : 1.f - lh;
                float wwt = (j & 1)  ? lw : 1.f - lw;
                int hc = min(max(hj, 0), H_DIM - 1);
                int wc = min(max(wj, 0), W_DIM - 1);
                cw[j] = v ? wh * wwt : 0.f;
                cb[j] = (tb + hc * W_DIM + wc) * 128 + lk * 32;   // byte offset
            }
        } else {
            int hj = h + kh - 1, wj = w + kw - 1;
            bool v = tv && (hj >= 0) && (hj < H_DIM) && (wj >= 0) && (wj < W_DIM);
            int hc = min(max(hj, 0), H_DIM - 1);
            int wc = min(max(wj, 0), W_DIM - 1);
            cw[0] = v ? 1.f : 0.f;
            cb[0] = (tb + hc * W_DIM + wc) * 128 + lk * 32;
        }
    };
    auto issue = [&]() {
        if (DEFORM) {
#pragma unroll
            for (int j = 0; j < 4; ++j) {
                g[2*j]     = *(const int4*)(xb + cb[j]);
                g[2*j + 1] = *(const int4*)(xb + cb[j] + 16);
            }
        } else {
            g[0] = *(const int4*)(xb + cb[0]);
            g[1] = *(const int4*)(xb + cb[0] + 16);
        }
    };

    // prologue
    if (DEFORM) {
        float2 o20 = *(const float2*)(offp);
        params(0, o20);
        issue();
        o2n = *(const float2*)(offp + 2);
    } else {
        params(0, o2n);
        issue();
    }

#pragma unroll 1
    for (int k = 0; k < NTAPS; ++k) {
        // ---- consume gathers of tap k -> wave-private LDS tile (bf16 [16][64])
        if (DEFORM) {
            float v[16];
#pragma unroll
            for (int i = 0; i < 16; ++i) v[i] = 0.f;
#pragma unroll
            for (int j = 0; j < 4; ++j) {
                float wj = cw[j];
#pragma unroll
                for (int p = 0; p < 2; ++p) {
                    int4 gg = g[2*j + p];
#pragma unroll
                    for (int d = 0; d < 4; ++d) {
                        unsigned ud = ((const unsigned*)&gg)[d];
                        float lo = __uint_as_float(ud << 16);
                        float hi = __uint_as_float(ud & 0xffff0000u);
                        v[p*8 + 2*d]     += wj * lo;
                        v[p*8 + 2*d + 1] += wj * hi;
                    }
                }
            }
            unsigned dw[8];
#pragma unroll
            for (int p = 0; p < 8; ++p) {
                __hip_bfloat162 h2 = __float22bfloat162_rn(make_float2(v[2*p], v[2*p+1]));
                dw[p] = *reinterpret_cast<unsigned*>(&h2);
            }
            *(int4*)(Sb + swz(lr, lk*32))      = make_int4(dw[0], dw[1], dw[2], dw[3]);
            *(int4*)(Sb + swz(lr, lk*32 + 16)) = make_int4(dw[4], dw[5], dw[6], dw[7]);
        } else {
            int4 z0 = g[0], z1 = g[1];
            if (cw[0] == 0.f) { z0 = make_int4(0,0,0,0); z1 = make_int4(0,0,0,0); }
            *(int4*)(Sb + swz(lr, lk*32))      = z0;
            *(int4*)(Sb + swz(lr, lk*32 + 16)) = z1;
        }

        // ---- prefetch tap k+1 (params + gather issue) before MFMA of tap k
        if (k < NTAPS - 1) {
            params(k + 1, o2n);
            issue();
            if (DEFORM && k < NTAPS - 2)
                o2n = *(const float2*)(offp + 2 * (k + 2));
        }

        // ---- MFMA of tap k (A from wave-private LDS, B direct from global/L1)
        bf16x8 a0 = *(const bf16x8*)(Sb + swz(lr, lk*16));         // ch 0..31
        bf16x8 a1 = *(const bf16x8*)(Sb + swz(lr, 64 + lk*16));    // ch 32..63
        const unsigned short* wb = Wt + k * 4096 + lr * 64 + lk * 8;
#pragma unroll
        for (int n = 0; n < 4; ++n) {
            bf16x8 b0 = *(const bf16x8*)(wb + n * 1024);
            bf16x8 b1 = *(const bf16x8*)(wb + n * 1024 + 32);
            acc[n] = __builtin_amdgcn_mfma_f32_16x16x32_bf16(a0, b0, acc[n], 0, 0, 0);
            acc[n] = __builtin_amdgcn_mfma_f32_16x16x32_bf16(a1, b1, acc[n], 0, 0, 0);
        }
    }

    // ---- epilogue.  C/D layout: col = lane&15 (out ch within n*16), row = lk*4+i (loc)
    float bv[4];
#pragma unroll
    for (int n = 0; n < 4; ++n) {
        int o = n * 16 + lr;
        bv[n] = (o < nbias) ? bias[o] : 0.f;
    }
    if (EPI == 0) {
#pragma unroll
        for (int n = 0; n < 4; ++n)
#pragma unroll
            for (int i = 0; i < 4; ++i) {
                int row = lk * 4 + i;
                outf[(size_t)(lbase + row) * 64 + n * 16 + lr] = acc[n][i] + bv[n];
            }
    } else if (EPI == 1) {
#pragma unroll
        for (int n = 0; n < 4; ++n)
#pragma unroll
            for (int i = 0; i < 4; ++i) {
                int row = lk * 4 + i;
                float vv = acc[n][i] + bv[n];
                vv = (vv > 0.f) ? vv : 0.1f * vv;
                __hip_bfloat16 hv = __float2bfloat16(vv);
                outh[(size_t)(lbase + row) * 64 + n * 16 + lr] = *reinterpret_cast<unsigned short*>(&hv);
            }
    } else {
        // transpose via wave-private LDS (rotation avoids bank conflicts), then NCDHW +resid
        float* tf = (float*)Sb;
#pragma unroll
        for (int n = 0; n < 4; ++n)
#pragma unroll
            for (int i = 0; i < 4; ++i) {
                int row = lk * 4 + i;
                int och = n * 16 + lr;
                tf[row * 64 + ((och + 2 * row) & 63)] = acc[n][i] + bv[n];
            }
        int j = lane & 15, gq = lane >> 4;
#pragma unroll
        for (int it = 0; it < 16; ++it) {
            int och = gq * 16 + it;
            float val = tf[j * 64 + ((och + 2 * j) & 63)];
            size_t gi = (size_t)och * L_DIM + lbase + j;
            outf[gi] = val + resid[gi];
        }
    }
}

// ---------------------------------------------------------------------------
extern "C" void kernel_launch(void* const* d_in, const int* in_sizes, int n_in,
                              void* d_out, int out_size, void* d_ws, size_t ws_size,
                              hipStream_t stream)
{
    const float* x     = (const float*)d_in[0];
    const float* woff0 = (const float*)d_in[1];
    const float* boff0 = (const float*)d_in[2];
    const float* w0    = (const float*)d_in[3];
    const float* b0    = (const float*)d_in[4];
    const float* woff1 = (const float*)d_in[5];
    const float* boff1 = (const float*)d_in[6];
    const float* w1    = (const float*)d_in[7];
    const float* b1    = (const float*)d_in[8];
    float* out = (float*)d_out;

    unsigned char* ws = (unsigned char*)d_ws;
    unsigned short* Wt  = (unsigned short*)ws;                  // 884736 B (4x bf16 [27][64][64])
    unsigned short* xt  = (unsigned short*)(ws + 884736);       // 8257536 B bf16 [L][64]
    unsigned short* y   = (unsigned short*)(ws + 9142272);      // 8257536 B bf16 [L][64]
    float*          offb= (float*)(ws + 17399808);              // 16515072 B f32 [L][64]

    prep_weights<<<1728, 256, 0, stream>>>(woff0, w0, woff1, w1, Wt);
    transpose_x<<<1008, 256, 0, stream>>>(x, (unsigned*)xt);

    const int grid = T_DIM * (HW / 64);   // 1008
    const int WSZ  = NTAPS * 64 * 64;     // 110592

    // layer 0
    dcn_wave<false, 0><<<grid, 256, 0, stream>>>(xt, nullptr, Wt,           boff0, 54, nullptr, offb, nullptr);
    dcn_wave<true,  1><<<grid, 256, 0, stream>>>(xt, offb,    Wt + WSZ,     b0,    64, nullptr, nullptr, y);
    // layer 1
    dcn_wave<false, 0><<<grid, 256, 0, stream>>>(y,  nullptr, Wt + 2 * WSZ, boff1, 54, nullptr, offb, nullptr);
    dcn_wave<true,  2><<<grid, 256, 0, stream>>>(y,  offb,    Wt + 3 * WSZ, b1,    64, x, out, nullptr);
}

// Round 4
// 300.229 us; speedup vs baseline: 2.1431x; 2.1431x over previous
//
#include <hip/hip_runtime.h>
#include <hip/hip_bf16.h>

#define T_DIM 7
#define H_DIM 96
#define W_DIM 96
#define HW    (H_DIM*W_DIM)          // 9216
#define L_DIM (T_DIM*HW)             // 64512
#define NTAPS 27

typedef __attribute__((ext_vector_type(8))) short bf16x8;
typedef __attribute__((ext_vector_type(4))) float f32x4;

// ---------------------------------------------------------------------------
// prep_weights: [O][C][27] fp32 -> [27][O(64-pad)][C] bf16, PRE-SWIZZLED:
// within each 128B row the 16B slot is rotated by (o & 7). Then LDS staging is
// a linear copy and swizzled ds_read_b128 is conflict-floor.
// ---------------------------------------------------------------------------
__global__ void prep_weights(const float* __restrict__ woff0,
                             const float* __restrict__ w0,
                             const float* __restrict__ woff1,
                             const float* __restrict__ w1,
                             unsigned short* __restrict__ dst)
{
    int idx = blockIdx.x * 256 + threadIdx.x;
    const int per = NTAPS * 64 * 64;           // 110592
    if (idx >= 4 * per) return;
    int which = idx / per;
    int r     = idx % per;
    int tap   = r / 4096;
    int o     = (r >> 6) & 63;
    int c     = r & 63;
    const float* src = (which == 0) ? woff0 : (which == 1) ? w0
                     : (which == 2) ? woff1 : w1;
    int omax = (which == 0 || which == 2) ? 54 : 64;
    float v = 0.f;
    if (o < omax) v = src[(o * 64 + c) * NTAPS + tap];
    __hip_bfloat16 h = __float2bfloat16(v);
    int pos = tap * 4096 + o * 64 + ((((c >> 3) + o) & 7) << 3) + (c & 7);
    dst[which * per + pos] = *reinterpret_cast<unsigned short*>(&h);
}

// ---------------------------------------------------------------------------
// transpose_x: x [C=64][L] fp32 -> xt [L][64] bf16 (packed dwords)
// ---------------------------------------------------------------------------
__global__ void transpose_x(const float* __restrict__ x, unsigned* __restrict__ xt2)
{
    __shared__ float tile[64][65];
    const int tid = threadIdx.x;
    const int lb  = blockIdx.x * 64;
    const int ln  = tid & 63;
    const int q   = tid >> 6;    // 0..3
#pragma unroll
    for (int i = 0; i < 16; ++i) {
        int c = q + 4 * i;
        tile[ln][c] = x[(size_t)c * L_DIM + lb + ln];
    }
    __syncthreads();
    const int ln2 = tid & 31, q2 = tid >> 5;   // 0..7
#pragma unroll
    for (int i = 0; i < 8; ++i) {
        int ll = q2 + 8 * i;
        __hip_bfloat162 h2 = __float22bfloat162_rn(make_float2(tile[ll][2*ln2], tile[ll][2*ln2+1]));
        xt2[(size_t)(lb + ll) * 32 + ln2] = *reinterpret_cast<unsigned*>(&h2);
    }
}

// ---------------------------------------------------------------------------
// dcn_reg: A-frags gathered DIRECTLY into registers (no LDS round-trip).
// Weights double-buffered in LDS (2 x 8KB), reg-routed 2 taps deep.
// One barrier per tap. Clean per-wave vmcnt FIFO (counted waits).
//   EPI: 0 = +bias -> f32 [loc][64]; 1 = +bias+leaky -> bf16 [loc][64];
//        2 = +bias+residual -> f32 NCDHW d_out
// ---------------------------------------------------------------------------
template<bool DEFORM, int EPI>
__global__ __launch_bounds__(256, DEFORM ? 3 : 4)
void dcn_reg(const unsigned short* __restrict__ xin,   // bf16 [L][64]
             const float* __restrict__ off,            // f32 [L][64] (DEFORM)
             const unsigned short* __restrict__ Wt,    // bf16 [27][64][64] swizzled
             const float* __restrict__ bias, int nbias,
             const float* __restrict__ resid,          // f32 NCDHW (EPI==2)
             float* __restrict__ outf,
             unsigned short* __restrict__ outh)
{
    __shared__ __align__(16) unsigned char smem[16384];   // 2 x 8KB weight bufs

    const int tid  = threadIdx.x;
    const int wave = tid >> 6, lane = tid & 63;
    const int lr   = lane & 15, lk = lane >> 4;

    const int nt    = HW / 64;                 // 144
    const int tile  = blockIdx.x % nt;
    const int t     = blockIdx.x / nt;
    const int wloc0 = tile * 64 + wave * 16;
    const int lbase = t * HW + wloc0;

    const int mypos = wloc0 + lr;
    const int h = mypos / W_DIM;
    const int w = mypos - h * W_DIM;

    f32x4 acc[4];
#pragma unroll
    for (int n = 0; n < 4; ++n) acc[n] = (f32x4){0.f, 0.f, 0.f, 0.f};

    const unsigned char* xb = (const unsigned char*)xin;
    const float* offp = DEFORM ? (off + (size_t)(lbase + lr) * 64) : nullptr;

    // swizzled slot offsets for B reads (row-invariant: n*16 % 8 == 0)
    const int s0 = ((lk + lr) & 7) << 4;
    const int s1 = ((lk + lr + 4) & 7) << 4;

    int4  g[8];
    int4  wA0, wA1, wB0, wB1;
    float cw[4];
    int   cb[4];
    float2 o2n = make_float2(0.f, 0.f);

    auto params = [&](int k, float2 o2) {
        int kt = k / 9; int r9 = k - kt * 9;
        int kh = r9 / 3; int kw = r9 - kh * 3;
        int tp = t + kt - 1;
        bool tv = (tp >= 0) && (tp < T_DIM);
        int tb = (tv ? tp : 0) * HW;
        if (DEFORM) {
            float ph = (float)(h + kh - 1) + o2.x;
            float pw = (float)(w + kw - 1) + o2.y;
            float h0f = floorf(ph), w0f = floorf(pw);
            float lh = ph - h0f, lw = pw - w0f;
            int h0 = (int)h0f, w0 = (int)w0f;
#pragma unroll
            for (int j = 0; j < 4; ++j) {
                int hj = h0 + (j >> 1), wj = w0 + (j & 1);
                bool v = tv && (hj >= 0) && (hj < H_DIM) && (wj >= 0) && (wj < W_DIM);
                float wh  = (j >> 1) ? lh : 1.f - lh;
                float wwt = (j & 1)  ? lw : 1.f - lw;
                int hc = min(max(hj, 0), H_DIM - 1);
                int wc = min(max(wj, 0), W_DIM - 1);
                cw[j] = v ? wh * wwt : 0.f;
                cb[j] = (tb + hc * W_DIM + wc) * 128 + lk * 16;   // byte offset
            }
        } else {
            int hj = h + kh - 1, wj = w + kw - 1;
            bool v = tv && (hj >= 0) && (hj < H_DIM) && (wj >= 0) && (wj < W_DIM);
            int hc = min(max(hj, 0), H_DIM - 1);
            int wc = min(max(wj, 0), W_DIM - 1);
            cw[0] = v ? 1.f : 0.f;
            cb[0] = (tb + hc * W_DIM + wc) * 128 + lk * 16;
        }
    };
    auto issue = [&]() {
        if (DEFORM) {
#pragma unroll
            for (int j = 0; j < 4; ++j) {
                g[2*j]     = *(const int4*)(xb + cb[j]);        // ch lk*8..+8
                g[2*j + 1] = *(const int4*)(xb + cb[j] + 64);   // ch 32+lk*8..+8
            }
        } else {
            g[0] = *(const int4*)(xb + cb[0]);
            g[1] = *(const int4*)(xb + cb[0] + 64);
        }
    };

    // ---- prologue: weights taps 0,1; gathers tap 0; stage tap 0 -> buf0
    {
        const int4* wp0 = (const int4*)(Wt);
        wA0 = wp0[2 * tid]; wA1 = wp0[2 * tid + 1];
        const int4* wp1 = (const int4*)(Wt + 4096);
        wB0 = wp1[2 * tid]; wB1 = wp1[2 * tid + 1];
    }
    if (DEFORM) {
        float2 o20 = *(const float2*)(offp);
        params(0, o20);
        issue();
        o2n = *(const float2*)(offp + 2);
    } else {
        params(0, o2n);
        issue();
    }
    *(int4*)(smem + tid * 32)      = wA0;
    *(int4*)(smem + tid * 32 + 16) = wA1;
    wA0 = wB0; wA1 = wB1;

#pragma unroll 1
    for (int k = 0; k < NTAPS; ++k) {
        // 1. issue weight loads for tap k+2
        if (k + 2 < NTAPS) {
            const int4* wp = (const int4*)(Wt + (size_t)(k + 2) * 4096);
            wB0 = wp[2 * tid]; wB1 = wp[2 * tid + 1];
        }

        // 2. consume gathers(k) -> A-frags in registers
        bf16x8 a0, a1;
        if (DEFORM) {
            float v[16];
#pragma unroll
            for (int i = 0; i < 16; ++i) v[i] = 0.f;
#pragma unroll
            for (int j = 0; j < 4; ++j) {
                float wj = cw[j];
#pragma unroll
                for (int p = 0; p < 2; ++p) {
                    int4 gg = g[2*j + p];
#pragma unroll
                    for (int d = 0; d < 4; ++d) {
                        unsigned ud = ((const unsigned*)&gg)[d];
                        float lo = __uint_as_float(ud << 16);
                        float hi = __uint_as_float(ud & 0xffff0000u);
                        v[p*8 + 2*d]     += wj * lo;
                        v[p*8 + 2*d + 1] += wj * hi;
                    }
                }
            }
            unsigned dw[8];
#pragma unroll
            for (int p = 0; p < 8; ++p) {
                __hip_bfloat162 h2 = __float22bfloat162_rn(make_float2(v[2*p], v[2*p+1]));
                dw[p] = *reinterpret_cast<unsigned*>(&h2);
            }
            int4 ia0 = make_int4(dw[0], dw[1], dw[2], dw[3]);
            int4 ia1 = make_int4(dw[4], dw[5], dw[6], dw[7]);
            a0 = *reinterpret_cast<bf16x8*>(&ia0);
            a1 = *reinterpret_cast<bf16x8*>(&ia1);
        } else {
            int4 z0 = g[0], z1 = g[1];
            if (cw[0] == 0.f) { z0 = make_int4(0,0,0,0); z1 = make_int4(0,0,0,0); }
            a0 = *reinterpret_cast<bf16x8*>(&z0);
            a1 = *reinterpret_cast<bf16x8*>(&z1);
        }

        // 3. params + issue gathers for tap k+1 (in flight across MFMA below)
        if (k + 1 < NTAPS) {
            params(k + 1, o2n);
            issue();
            if (DEFORM && k < NTAPS - 2)
                o2n = *(const float2*)(offp + 2 * (k + 2));
        }

        // 4. barrier, then stage weights tap k+1 into the other buffer
        __syncthreads();
        if (k + 1 < NTAPS) {
            unsigned char* bw = smem + (((k + 1) & 1) << 13);
            *(int4*)(bw + tid * 32)      = wA0;
            *(int4*)(bw + tid * 32 + 16) = wA1;
            wA0 = wB0; wA1 = wB1;
        }

        // 5. B-frag reads (conflict-floor b128) + 8 MFMAs
        const unsigned char* br = smem + ((k & 1) << 13) + lr * 128;
#pragma unroll
        for (int n = 0; n < 4; ++n) {
            bf16x8 b0 = *(const bf16x8*)(br + n * 2048 + s0);
            bf16x8 b1 = *(const bf16x8*)(br + n * 2048 + s1);
            acc[n] = __builtin_amdgcn_mfma_f32_16x16x32_bf16(a0, b0, acc[n], 0, 0, 0);
            acc[n] = __builtin_amdgcn_mfma_f32_16x16x32_bf16(a1, b1, acc[n], 0, 0, 0);
        }
    }

    // ---- epilogue. C/D: col = lr (out ch within n*16), row = lk*4+i (loc)
    float bv[4];
#pragma unroll
    for (int n = 0; n < 4; ++n) {
        int o = n * 16 + lr;
        bv[n] = (o < nbias) ? bias[o] : 0.f;
    }
    if (EPI == 0) {
#pragma unroll
        for (int n = 0; n < 4; ++n)
#pragma unroll
            for (int i = 0; i < 4; ++i) {
                int row = lk * 4 + i;
                outf[(size_t)(lbase + row) * 64 + n * 16 + lr] = acc[n][i] + bv[n];
            }
    } else if (EPI == 1) {
#pragma unroll
        for (int n = 0; n < 4; ++n)
#pragma unroll
            for (int i = 0; i < 4; ++i) {
                int row = lk * 4 + i;
                float vv = acc[n][i] + bv[n];
                vv = (vv > 0.f) ? vv : 0.1f * vv;
                __hip_bfloat16 hv = __float2bfloat16(vv);
                outh[(size_t)(lbase + row) * 64 + n * 16 + lr] = *reinterpret_cast<unsigned short*>(&hv);
            }
    } else {
        __syncthreads();   // weight bufs dead; reuse smem per-wave for transpose
        float* tf = (float*)(smem + wave * 4096);
#pragma unroll
        for (int n = 0; n < 4; ++n)
#pragma unroll
            for (int i = 0; i < 4; ++i) {
                int row = lk * 4 + i;
                int och = n * 16 + lr;
                tf[row * 64 + ((och + 2 * row) & 63)] = acc[n][i] + bv[n];
            }
        int j = lane & 15, gq = lane >> 4;
#pragma unroll
        for (int it = 0; it < 16; ++it) {
            int och = gq * 16 + it;
            float val = tf[j * 64 + ((och + 2 * j) & 63)];
            size_t gi = (size_t)och * L_DIM + lbase + j;
            outf[gi] = val + resid[gi];
        }
    }
}

// ---------------------------------------------------------------------------
extern "C" void kernel_launch(void* const* d_in, const int* in_sizes, int n_in,
                              void* d_out, int out_size, void* d_ws, size_t ws_size,
                              hipStream_t stream)
{
    const float* x     = (const float*)d_in[0];
    const float* woff0 = (const float*)d_in[1];
    const float* boff0 = (const float*)d_in[2];
    const float* w0    = (const float*)d_in[3];
    const float* b0    = (const float*)d_in[4];
    const float* woff1 = (const float*)d_in[5];
    const float* boff1 = (const float*)d_in[6];
    const float* w1    = (const float*)d_in[7];
    const float* b1    = (const float*)d_in[8];
    float* out = (float*)d_out;

    unsigned char* ws = (unsigned char*)d_ws;
    unsigned short* Wt  = (unsigned short*)ws;                  // 884736 B (4x bf16 [27][64][64] swz)
    unsigned short* xt  = (unsigned short*)(ws + 884736);       // 8257536 B bf16 [L][64]
    unsigned short* y   = (unsigned short*)(ws + 9142272);      // 8257536 B bf16 [L][64]
    float*          offb= (float*)(ws + 17399808);              // 16515072 B f32 [L][64]

    prep_weights<<<1728, 256, 0, stream>>>(woff0, w0, woff1, w1, Wt);
    transpose_x<<<1008, 256, 0, stream>>>(x, (unsigned*)xt);

    const int grid = T_DIM * (HW / 64);   // 1008
    const int WSZ  = NTAPS * 64 * 64;     // 110592

    // layer 0
    dcn_reg<false, 0><<<grid, 256, 0, stream>>>(xt, nullptr, Wt,           boff0, 54, nullptr, offb, nullptr);
    dcn_reg<true,  1><<<grid, 256, 0, stream>>>(xt, offb,    Wt + WSZ,     b0,    64, nullptr, nullptr, y);
    // layer 1
    dcn_reg<false, 0><<<grid, 256, 0, stream>>>(y,  nullptr, Wt + 2 * WSZ, boff1, 54, nullptr, offb, nullptr);
    dcn_reg<true,  2><<<grid, 256, 0, stream>>>(y,  offb,    Wt + 3 * WSZ, b1,    64, x, out, nullptr);
}

// Round 5
// 297.778 us; speedup vs baseline: 2.1607x; 1.0082x over previous
//
#include <hip/hip_runtime.h>
#include <hip/hip_fp16.h>

#define T_DIM 7
#define H_DIM 96
#define W_DIM 96
#define HW    (H_DIM*W_DIM)          // 9216
#define L_DIM (T_DIM*HW)             // 64512
#define NTAPS 27

typedef __attribute__((ext_vector_type(8))) _Float16 f16x8;
typedef __attribute__((ext_vector_type(4))) float f32x4;

// barrier that does NOT drain vmcnt (keeps global prefetches in flight).
// LDS producer->consumer only needs lgkmcnt(0) before s_barrier.
__device__ __forceinline__ void lds_barrier() {
    asm volatile("s_waitcnt lgkmcnt(0)" ::: "memory");
    __builtin_amdgcn_s_barrier();
    __builtin_amdgcn_sched_barrier(0);
}

// ---------------------------------------------------------------------------
// prep_weights: [O][C][27] fp32 -> [27][O(64-pad)][C] f16, PRE-SWIZZLED:
// 16B slot within each 128B row rotated by 2*o  ->  every 16-lane read phase
// hits each bank-pair exactly 2x (conflict-free per m136).
// ---------------------------------------------------------------------------
__global__ void prep_weights(const float* __restrict__ woff0,
                             const float* __restrict__ w0,
                             const float* __restrict__ woff1,
                             const float* __restrict__ w1,
                             unsigned short* __restrict__ dst)
{
    int idx = blockIdx.x * 256 + threadIdx.x;
    const int per = NTAPS * 64 * 64;           // 110592
    if (idx >= 4 * per) return;
    int which = idx / per;
    int r     = idx % per;
    int tap   = r / 4096;
    int o     = (r >> 6) & 63;
    int c     = r & 63;
    const float* src = (which == 0) ? woff0 : (which == 1) ? w0
                     : (which == 2) ? woff1 : w1;
    int omax = (which == 0 || which == 2) ? 54 : 64;
    float v = 0.f;
    if (o < omax) v = src[(o * 64 + c) * NTAPS + tap];
    __half h = __float2half(v);
    int slot = (((c >> 3) + 2 * o) & 7);
    int pos  = tap * 4096 + o * 64 + slot * 8 + (c & 7);
    dst[which * per + pos] = __half_as_ushort(h);
}

// ---------------------------------------------------------------------------
// transpose_x: x [C=64][L] fp32 -> xt [L][64] f16 (packed dwords)
// ---------------------------------------------------------------------------
__global__ void transpose_x(const float* __restrict__ x, unsigned* __restrict__ xt2)
{
    __shared__ float tile[64][65];
    const int tid = threadIdx.x;
    const int lb  = blockIdx.x * 64;
    const int ln  = tid & 63;
    const int q   = tid >> 6;    // 0..3
#pragma unroll
    for (int i = 0; i < 16; ++i) {
        int c = q + 4 * i;
        tile[ln][c] = x[(size_t)c * L_DIM + lb + ln];
    }
    __syncthreads();
    const int ln2 = tid & 31, q2 = tid >> 5;   // 0..7
#pragma unroll
    for (int i = 0; i < 8; ++i) {
        int ll = q2 + 8 * i;
        __half2 h2 = __float22half2_rn(make_float2(tile[ll][2*ln2], tile[ll][2*ln2+1]));
        xt2[(size_t)(lb + ll) * 32 + ln2] = *reinterpret_cast<unsigned*>(&h2);
    }
}

// ---------------------------------------------------------------------------
// dcn_reg: A-frags gathered directly into registers; packed-f16 lerp; weights
// double-buffered in LDS (2 x 8KB) with raw-barrier (vmcnt stays in flight).
//   EPI: 0 = +bias -> f32 [loc][64]; 1 = +bias+leaky -> f16 [loc][64];
//        2 = +bias+residual -> f32 NCDHW d_out
// ---------------------------------------------------------------------------
template<bool DEFORM, int EPI>
__global__ __launch_bounds__(256, DEFORM ? 3 : 4)
void dcn_reg(const unsigned short* __restrict__ xin,   // f16 [L][64]
             const float* __restrict__ off,            // f32 [L][64] (DEFORM)
             const unsigned short* __restrict__ Wt,    // f16 [27][64][64] swizzled
             const float* __restrict__ bias, int nbias,
             const float* __restrict__ resid,          // f32 NCDHW (EPI==2)
             float* __restrict__ outf,
             unsigned short* __restrict__ outh)
{
    __shared__ __align__(16) unsigned char smem[16384];   // 2 x 8KB weight bufs

    const int tid  = threadIdx.x;
    const int wave = tid >> 6, lane = tid & 63;
    const int lr   = lane & 15, lk = lane >> 4;

    const int nt    = HW / 64;                 // 144
    const int tile  = blockIdx.x % nt;
    const int t     = blockIdx.x / nt;
    const int wloc0 = tile * 64 + wave * 16;
    const int lbase = t * HW + wloc0;

    const int mypos = wloc0 + lr;
    const int h = mypos / W_DIM;
    const int w = mypos - h * W_DIM;

    f32x4 acc[4];
#pragma unroll
    for (int n = 0; n < 4; ++n) acc[n] = (f32x4){0.f, 0.f, 0.f, 0.f};

    const unsigned char* xb = (const unsigned char*)xin;
    const float* offp = DEFORM ? (off + (size_t)(lbase + lr) * 64) : nullptr;

    // swizzled slot offsets for B reads (row term 2*(n*16+lr) == 2*lr mod 8)
    const int s0 = ((lk + 2 * lr) & 7) << 4;
    const int s1 = ((lk + 4 + 2 * lr) & 7) << 4;

    int4    g[8];
    int4    wA0, wA1, wB0, wB1;
    __half2 cwh[4];
    float   cw0;
    int     cb[4];
    float2  o2n = make_float2(0.f, 0.f);

    auto params = [&](int k, float2 o2) {
        int kt = k / 9; int r9 = k - kt * 9;
        int kh = r9 / 3; int kw = r9 - kh * 3;
        int tp = t + kt - 1;
        bool tv = (tp >= 0) && (tp < T_DIM);
        int tb = (tv ? tp : 0) * HW;
        if (DEFORM) {
            float ph = (float)(h + kh - 1) + o2.x;
            float pw = (float)(w + kw - 1) + o2.y;
            float h0f = floorf(ph), w0f = floorf(pw);
            float lh = ph - h0f, lw = pw - w0f;
            int h0 = (int)h0f, w0 = (int)w0f;
#pragma unroll
            for (int j = 0; j < 4; ++j) {
                int hj = h0 + (j >> 1), wj = w0 + (j & 1);
                bool v = tv && (hj >= 0) && (hj < H_DIM) && (wj >= 0) && (wj < W_DIM);
                float wh  = (j >> 1) ? lh : 1.f - lh;
                float wwt = (j & 1)  ? lw : 1.f - lw;
                int hc = min(max(hj, 0), H_DIM - 1);
                int wc = min(max(wj, 0), W_DIM - 1);
                cwh[j] = __float2half2_rn(v ? wh * wwt : 0.f);
                cb[j]  = (tb + hc * W_DIM + wc) * 128 + lk * 16;   // byte offset
            }
        } else {
            int hj = h + kh - 1, wj = w + kw - 1;
            bool v = tv && (hj >= 0) && (hj < H_DIM) && (wj >= 0) && (wj < W_DIM);
            int hc = min(max(hj, 0), H_DIM - 1);
            int wc = min(max(wj, 0), W_DIM - 1);
            cw0   = v ? 1.f : 0.f;
            cb[0] = (tb + hc * W_DIM + wc) * 128 + lk * 16;
        }
    };
    auto issue = [&]() {
        if (DEFORM) {
#pragma unroll
            for (int j = 0; j < 4; ++j) {
                g[2*j]     = *(const int4*)(xb + cb[j]);        // ch lk*8..+8
                g[2*j + 1] = *(const int4*)(xb + cb[j] + 64);   // ch 32+lk*8..+8
            }
        } else {
            g[0] = *(const int4*)(xb + cb[0]);
            g[1] = *(const int4*)(xb + cb[0] + 64);
        }
    };

    // ---- prologue: weights taps 0,1; gathers tap 0; stage tap 0 -> buf0
    {
        const int4* wp0 = (const int4*)(Wt);
        wA0 = wp0[2 * tid]; wA1 = wp0[2 * tid + 1];
        const int4* wp1 = (const int4*)(Wt + 4096);
        wB0 = wp1[2 * tid]; wB1 = wp1[2 * tid + 1];
    }
    if (DEFORM) {
        float2 o20 = *(const float2*)(offp);
        params(0, o20);
        issue();
        o2n = *(const float2*)(offp + 2);
    } else {
        params(0, o2n);
        issue();
    }
    *(int4*)(smem + tid * 32)      = wA0;
    *(int4*)(smem + tid * 32 + 16) = wA1;
    wA0 = wB0; wA1 = wB1;

#pragma unroll 1
    for (int k = 0; k < NTAPS; ++k) {
        // 1. issue weight loads for tap k+2
        if (k + 2 < NTAPS) {
            const int4* wp = (const int4*)(Wt + (size_t)(k + 2) * 4096);
            wB0 = wp[2 * tid]; wB1 = wp[2 * tid + 1];
        }

        // 2. consume gathers(k) -> A-frags via packed-f16 lerp (v_pk_fma_f16)
        f16x8 a0, a1;
        if (DEFORM) {
            __align__(16) __half2 va[8];
            const __half2 z2 = __float2half2_rn(0.f);
#pragma unroll
            for (int p = 0; p < 8; ++p) va[p] = z2;
#pragma unroll
            for (int j = 0; j < 4; ++j) {
                const __half2* g0 = (const __half2*)&g[2*j];
                const __half2* g1 = (const __half2*)&g[2*j + 1];
#pragma unroll
                for (int d = 0; d < 4; ++d) {
                    va[d]     = __hfma2(g0[d], cwh[j], va[d]);
                    va[4 + d] = __hfma2(g1[d], cwh[j], va[4 + d]);
                }
            }
            a0 = *reinterpret_cast<f16x8*>(&va[0]);
            a1 = *reinterpret_cast<f16x8*>(&va[4]);
        } else {
            int4 z0 = g[0], z1 = g[1];
            if (cw0 == 0.f) { z0 = make_int4(0,0,0,0); z1 = make_int4(0,0,0,0); }
            a0 = *reinterpret_cast<f16x8*>(&z0);
            a1 = *reinterpret_cast<f16x8*>(&z1);
        }

        // 3. params + issue gathers for tap k+1 (stay in flight across barrier)
        if (k + 1 < NTAPS) {
            params(k + 1, o2n);
            issue();
            if (DEFORM && k < NTAPS - 2)
                o2n = *(const float2*)(offp + 2 * (k + 2));
        }

        // 4. raw barrier (lgkm only — vmcnt prefetches survive), then stage k+1
        lds_barrier();
        if (k + 1 < NTAPS) {
            unsigned char* bw = smem + (((k + 1) & 1) << 13);
            *(int4*)(bw + tid * 32)      = wA0;
            *(int4*)(bw + tid * 32 + 16) = wA1;
            wA0 = wB0; wA1 = wB1;
        }

        // 5. B-frag reads (2-way, free) + 8 MFMAs
        const unsigned char* br = smem + ((k & 1) << 13) + lr * 128;
#pragma unroll
        for (int n = 0; n < 4; ++n) {
            f16x8 b0 = *(const f16x8*)(br + n * 2048 + s0);
            f16x8 b1 = *(const f16x8*)(br + n * 2048 + s1);
            acc[n] = __builtin_amdgcn_mfma_f32_16x16x32_f16(a0, b0, acc[n], 0, 0, 0);
            acc[n] = __builtin_amdgcn_mfma_f32_16x16x32_f16(a1, b1, acc[n], 0, 0, 0);
        }
    }

    // ---- epilogue. C/D: col = lr (out ch within n*16), row = lk*4+i (loc)
    float bv[4];
#pragma unroll
    for (int n = 0; n < 4; ++n) {
        int o = n * 16 + lr;
        bv[n] = (o < nbias) ? bias[o] : 0.f;
    }
    if (EPI == 0) {
#pragma unroll
        for (int n = 0; n < 4; ++n)
#pragma unroll
            for (int i = 0; i < 4; ++i) {
                int row = lk * 4 + i;
                outf[(size_t)(lbase + row) * 64 + n * 16 + lr] = acc[n][i] + bv[n];
            }
    } else if (EPI == 1) {
#pragma unroll
        for (int n = 0; n < 4; ++n)
#pragma unroll
            for (int i = 0; i < 4; ++i) {
                int row = lk * 4 + i;
                float vv = acc[n][i] + bv[n];
                vv = (vv > 0.f) ? vv : 0.1f * vv;
                outh[(size_t)(lbase + row) * 64 + n * 16 + lr] = __half_as_ushort(__float2half(vv));
            }
    } else {
        __syncthreads();   // weight bufs dead; reuse smem per-wave for transpose
        float* tf = (float*)(smem + wave * 4096);
#pragma unroll
        for (int n = 0; n < 4; ++n)
#pragma unroll
            for (int i = 0; i < 4; ++i) {
                int row = lk * 4 + i;
                int och = n * 16 + lr;
                tf[row * 64 + ((och + 2 * row) & 63)] = acc[n][i] + bv[n];
            }
        int j = lane & 15, gq = lane >> 4;
#pragma unroll
        for (int it = 0; it < 16; ++it) {
            int och = gq * 16 + it;
            float val = tf[j * 64 + ((och + 2 * j) & 63)];
            size_t gi = (size_t)och * L_DIM + lbase + j;
            outf[gi] = val + resid[gi];
        }
    }
}

// ---------------------------------------------------------------------------
extern "C" void kernel_launch(void* const* d_in, const int* in_sizes, int n_in,
                              void* d_out, int out_size, void* d_ws, size_t ws_size,
                              hipStream_t stream)
{
    const float* x     = (const float*)d_in[0];
    const float* woff0 = (const float*)d_in[1];
    const float* boff0 = (const float*)d_in[2];
    const float* w0    = (const float*)d_in[3];
    const float* b0    = (const float*)d_in[4];
    const float* woff1 = (const float*)d_in[5];
    const float* boff1 = (const float*)d_in[6];
    const float* w1    = (const float*)d_in[7];
    const float* b1    = (const float*)d_in[8];
    float* out = (float*)d_out;

    unsigned char* ws = (unsigned char*)d_ws;
    unsigned short* Wt  = (unsigned short*)ws;                  // 884736 B (4x f16 [27][64][64] swz)
    unsigned short* xt  = (unsigned short*)(ws + 884736);       // 8257536 B f16 [L][64]
    unsigned short* y   = (unsigned short*)(ws + 9142272);      // 8257536 B f16 [L][64]
    float*          offb= (float*)(ws + 17399808);              // 16515072 B f32 [L][64]

    prep_weights<<<1728, 256, 0, stream>>>(woff0, w0, woff1, w1, Wt);
    transpose_x<<<1008, 256, 0, stream>>>(x, (unsigned*)xt);

    const int grid = T_DIM * (HW / 64);   // 1008
    const int WSZ  = NTAPS * 64 * 64;     // 110592

    // layer 0
    dcn_reg<false, 0><<<grid, 256, 0, stream>>>(xt, nullptr, Wt,           boff0, 54, nullptr, offb, nullptr);
    dcn_reg<true,  1><<<grid, 256, 0, stream>>>(xt, offb,    Wt + WSZ,     b0,    64, nullptr, nullptr, y);
    // layer 1
    dcn_reg<false, 0><<<grid, 256, 0, stream>>>(y,  nullptr, Wt + 2 * WSZ, boff1, 54, nullptr, offb, nullptr);
    dcn_reg<true,  2><<<grid, 256, 0, stream>>>(y,  offb,    Wt + 3 * WSZ, b1,    64, x, out, nullptr);
}